// Round 3
// baseline (5619.367 us; speedup 1.0000x reference)
//
#include <hip/hip_runtime.h>
#include <stdint.h>

typedef unsigned short u16;
typedef unsigned short u16x4 __attribute__((ext_vector_type(4)));
typedef unsigned short u16x8 __attribute__((ext_vector_type(8)));
typedef short bf16x8 __attribute__((ext_vector_type(8)));
typedef float f32x4 __attribute__((ext_vector_type(4)));

#define DEVINL __device__ __forceinline__

DEVINL float b2f(u16 u) {
  union { uint32_t u; float f; } c; c.u = ((uint32_t)u) << 16; return c.f;
}
DEVINL u16 f2b(float f) {
  union { float f; uint32_t u; } c; c.f = f;
  uint32_t u = c.u;
  u += 0x7fffu + ((u >> 16) & 1u);   // RNE
  return (u16)(u >> 16);
}

DEVINL void async16(const void* g, void* l) {
  __builtin_amdgcn_global_load_lds((__attribute__((address_space(1))) void*)g,
                                   (__attribute__((address_space(3))) void*)l,
                                   16, 0, 0);
}

DEVINL float rdlane(float v, int lane) {
  return __int_as_float(__builtin_amdgcn_readlane(__float_as_int(v), lane));
}

// =====================================================================
// f32 -> bf16 convert (weights). n % 4 == 0; grid covers n/4 threads.
// =====================================================================
__global__ __launch_bounds__(256) void cvt_f32_bf16(const float* __restrict__ s,
                                                    u16* __restrict__ d, int n4)
{
  int i = blockIdx.x * 256 + threadIdx.x;
  if (i >= n4) return;
  f32x4 v = *(const f32x4*)(s + (size_t)i * 4);
  u16x4 o;
  o[0] = f2b(v[0]); o[1] = f2b(v[1]); o[2] = f2b(v[2]); o[3] = f2b(v[3]);
  *(u16x4*)(d + (size_t)i * 4) = o;
}

// =====================================================================
// LayerNorm: f32 in -> bf16 out. One row (2048) per block.
// =====================================================================
__global__ __launch_bounds__(256) void ln_plain(const float* __restrict__ xin,
                                                const float* __restrict__ w,
                                                const float* __restrict__ b,
                                                u16* __restrict__ out)
{
  __shared__ float red[8];
  const size_t base = (size_t)blockIdx.x * 2048;
  const int tid = threadIdx.x;
  f32x4 r0 = *(const f32x4*)(xin + base + tid * 8);
  f32x4 r1 = *(const f32x4*)(xin + base + tid * 8 + 4);
  float f[8] = {r0[0], r0[1], r0[2], r0[3], r1[0], r1[1], r1[2], r1[3]};
  float s = 0.f, s2 = 0.f;
#pragma unroll
  for (int u = 0; u < 8; ++u) { s += f[u]; s2 += f[u] * f[u]; }
#pragma unroll
  for (int o = 32; o; o >>= 1) { s += __shfl_down(s, o, 64); s2 += __shfl_down(s2, o, 64); }
  if ((tid & 63) == 0) { red[tid >> 6] = s; red[4 + (tid >> 6)] = s2; }
  __syncthreads();
  s = red[0] + red[1] + red[2] + red[3];
  s2 = red[4] + red[5] + red[6] + red[7];
  const float m = s * (1.f / 2048.f);
  const float rs = rsqrtf(s2 * (1.f / 2048.f) - m * m + 1e-5f);
  u16x8 ov;
#pragma unroll
  for (int u = 0; u < 8; ++u) {
    int c = tid * 8 + u;
    ov[u] = f2b((f[u] - m) * rs * w[c] + b[c]);
  }
  *(u16x8*)(out + base + tid * 8) = ov;
}

// =====================================================================
// Fused LN + token-shift mix. xin is bf16 (x0/x1 in ws); params f32.
// prev = (t==0) ? f32 state : LN(xin[t-1]). stout: f32 last-row xn.
// =====================================================================
template <int NOUT>
__global__ __launch_bounds__(256) void ln_mix(const u16* __restrict__ xin,
                                              const float* __restrict__ lnw,
                                              const float* __restrict__ lnb,
                                              const float* __restrict__ prevst,
                                              const float* __restrict__ t0,
                                              const float* __restrict__ t1,
                                              const float* __restrict__ t2,
                                              const float* __restrict__ t3,
                                              u16* __restrict__ o0, u16* __restrict__ o1,
                                              u16* __restrict__ o2, u16* __restrict__ o3,
                                              float* __restrict__ stout)
{
  __shared__ float red[8];
  const int row = blockIdx.x;
  const int b = row >> 11, t = row & 2047;
  const int tid = threadIdx.x;
  const size_t base = (size_t)row * 2048;
  const int wv = tid >> 6, lane = tid & 63;

  u16x8 cr = *(const u16x8*)(xin + base + tid * 8);
  float cf[8];
  float s = 0.f, s2 = 0.f;
#pragma unroll
  for (int u = 0; u < 8; ++u) { cf[u] = b2f(cr[u]); s += cf[u]; s2 += cf[u] * cf[u]; }
#pragma unroll
  for (int o = 32; o; o >>= 1) { s += __shfl_down(s, o, 64); s2 += __shfl_down(s2, o, 64); }
  if (lane == 0) { red[wv] = s; red[4 + wv] = s2; }
  __syncthreads();
  s = red[0] + red[1] + red[2] + red[3];
  s2 = red[4] + red[5] + red[6] + red[7];
  float m = s * (1.f / 2048.f);
  float rs = rsqrtf(s2 * (1.f / 2048.f) - m * m + 1e-5f);
  float xn_t[8];
#pragma unroll
  for (int u = 0; u < 8; ++u) {
    int c = tid * 8 + u;
    xn_t[u] = (cf[u] - m) * rs * lnw[c] + lnb[c];
  }

  float xn_p[8];
  if (t == 0) {
#pragma unroll
    for (int u = 0; u < 8; ++u) xn_p[u] = prevst[(size_t)b * 2048 + tid * 8 + u];
  } else {
    u16x8 pr = *(const u16x8*)(xin + base - 2048 + tid * 8);
    float pf[8];
    float ps = 0.f, ps2 = 0.f;
#pragma unroll
    for (int u = 0; u < 8; ++u) { pf[u] = b2f(pr[u]); ps += pf[u]; ps2 += pf[u] * pf[u]; }
#pragma unroll
    for (int o = 32; o; o >>= 1) { ps += __shfl_down(ps, o, 64); ps2 += __shfl_down(ps2, o, 64); }
    __syncthreads();
    if (lane == 0) { red[wv] = ps; red[4 + wv] = ps2; }
    __syncthreads();
    ps = red[0] + red[1] + red[2] + red[3];
    ps2 = red[4] + red[5] + red[6] + red[7];
    float pm = ps * (1.f / 2048.f);
    float prs = rsqrtf(ps2 * (1.f / 2048.f) - pm * pm + 1e-5f);
#pragma unroll
    for (int u = 0; u < 8; ++u) {
      int c = tid * 8 + u;
      xn_p[u] = (pf[u] - pm) * prs * lnw[c] + lnb[c];
    }
  }

  u16x8 v0, v1, v2, v3;
#pragma unroll
  for (int u = 0; u < 8; ++u) {
    int c = tid * 8 + u;
    float a = xn_t[u], p = xn_p[u], d = a - p;
    v0[u] = f2b(p + d * t0[c]);
    v1[u] = f2b(p + d * t1[c]);
    if (NOUT == 4) {
      v2[u] = f2b(p + d * t2[c]);
      v3[u] = f2b(p + d * t3[c]);
    }
  }
  *(u16x8*)(o0 + base + tid * 8) = v0;
  *(u16x8*)(o1 + base + tid * 8) = v1;
  if (NOUT == 4) {
    *(u16x8*)(o2 + base + tid * 8) = v2;
    *(u16x8*)(o3 + base + tid * 8) = v3;
  }
  if (t == 2047) {
#pragma unroll
    for (int u = 0; u < 8; ++u) stout[(size_t)b * 2048 + tid * 8 + u] = xn_t[u];
  }
}

// =====================================================================
// bf16 GEMM: C[M,N] = epi( A[M,K] @ B[N,K]^T ), m97 structure.
// EPI: 0 plain, 1 silu, 2 relu^2, 3 sigmoid, 4 res+acc, 5 res+sig*acc
// F32OUT: write float32 output (else bf16).
// =====================================================================
template <int EPI, bool F32OUT>
__global__ __launch_bounds__(256) void gemm_bt(const u16* __restrict__ A,
                                               const u16* __restrict__ B,
                                               void* __restrict__ Cout,
                                               const u16* __restrict__ res,
                                               const u16* __restrict__ sig,
                                               int M, int N, int K)
{
  __shared__ short As[128 * 32];
  __shared__ short Bs[128 * 32];
  const int tid = threadIdx.x;
  const int lane = tid & 63;
  const int w = tid >> 6;
  const int wm = w >> 1, wn = w & 1;
  const int m0 = blockIdx.y * 128, n0 = blockIdx.x * 128;

  f32x4 acc[4][4];
#pragma unroll
  for (int mi = 0; mi < 4; ++mi)
#pragma unroll
    for (int ni = 0; ni < 4; ++ni) acc[mi][ni] = 0.f;

  const size_t a_goff = (size_t)(m0 + 32 * w + (lane >> 2)) * (size_t)K + (lane & 3) * 8;
  const size_t b_goff = (size_t)(n0 + 32 * w + (lane >> 2)) * (size_t)K + (lane & 3) * 8;
  short* asBase = &As[(2 * w) * 512];
  short* bsBase = &Bs[(2 * w) * 512];

  const int kq = (lane >> 4) * 8;
  const int am = wm * 64 + (lane & 15);
  const int bn = wn * 64 + (lane & 15);

  for (int k0 = 0; k0 < K; k0 += 32) {
    async16(A + a_goff + k0, asBase);
    async16(A + a_goff + (size_t)16 * K + k0, asBase + 512);
    async16(B + b_goff + k0, bsBase);
    async16(B + b_goff + (size_t)16 * K + k0, bsBase + 512);
    __syncthreads();
    bf16x8 af[4], bfr[4];
#pragma unroll
    for (int mi = 0; mi < 4; ++mi) af[mi] = *(const bf16x8*)&As[(am + mi * 16) * 32 + kq];
#pragma unroll
    for (int ni = 0; ni < 4; ++ni) bfr[ni] = *(const bf16x8*)&Bs[(bn + ni * 16) * 32 + kq];
#pragma unroll
    for (int mi = 0; mi < 4; ++mi)
#pragma unroll
      for (int ni = 0; ni < 4; ++ni)
        acc[mi][ni] = __builtin_amdgcn_mfma_f32_16x16x32_bf16(af[mi], bfr[ni], acc[mi][ni], 0, 0, 0);
    __syncthreads();
  }

  const int erow0 = m0 + wm * 64 + (lane >> 4) * 4;
  const int ecol0 = n0 + wn * 64 + (lane & 15);
#pragma unroll
  for (int mi = 0; mi < 4; ++mi) {
#pragma unroll
    for (int ni = 0; ni < 4; ++ni) {
#pragma unroll
      for (int r = 0; r < 4; ++r) {
        size_t idx = (size_t)(erow0 + mi * 16 + r) * (size_t)N + (ecol0 + ni * 16);
        float xv = acc[mi][ni][r];
        if (EPI == 1) xv = xv / (1.f + __expf(-xv));
        else if (EPI == 2) { float tt = fmaxf(xv, 0.f); xv = tt * tt; }
        else if (EPI == 3) xv = 1.f / (1.f + __expf(-xv));
        else if (EPI == 4) xv = b2f(res[idx]) + xv;
        else if (EPI == 5) xv = b2f(res[idx]) + b2f(sig[idx]) * xv;
        if (F32OUT) ((float*)Cout)[idx] = xv;
        else ((u16*)Cout)[idx] = f2b(xv);
      }
    }
  }
}

// =====================================================================
// WKV scan: one (b,h) per block; wave w owns channels [16w,16w+16),
// lane j = state column S[i][j].  r,k,v bf16; state/params f32.
// =====================================================================
__global__ __launch_bounds__(256) void wkv_scan(const u16* __restrict__ r,
                                                const u16* __restrict__ k,
                                                const u16* __restrict__ v,
                                                const float* __restrict__ td,
                                                const float* __restrict__ tf,
                                                const float* __restrict__ st0,
                                                u16* __restrict__ y,
                                                float* __restrict__ wkv_out)
{
  __shared__ float red[2][256];
  const int bh = blockIdx.x;
  const int b = bh >> 5, h = bh & 31;
  const int tid = threadIdx.x;
  const int w = tid >> 6, lane = tid & 63;
  const int i0 = w * 16;
  const int isub = lane & 15;

  const float wdec = expf(-expf(td[h * 64 + i0 + isub]));
  const float uv   = tf[h * 64 + i0 + isub];
  float sw[16];
#pragma unroll
  for (int ii = 0; ii < 16; ++ii) sw[ii] = rdlane(wdec, ii);

  float S[16];
  const size_t stb = ((size_t)bh * 64 + i0) * 64 + lane;
#pragma unroll
  for (int ii = 0; ii < 16; ++ii) S[ii] = st0[stb + (size_t)ii * 64];

  const size_t rowbase = (size_t)b * 2048 * 2048 + h * 64;
  const u16* rp = r + rowbase + i0 + isub;
  const u16* kp = k + rowbase + i0 + isub;
  const u16* vp = v + rowbase + lane;
  u16* yp = y + rowbase + lane;

  float rv = b2f(rp[0]), kv = b2f(kp[0]), vv = b2f(vp[0]);
#pragma unroll 1
  for (int t = 0; t < 2048; ++t) {
    float rn = 0.f, kn = 0.f, vn = 0.f;
    if (t + 1 < 2048) { rn = b2f(rp[2048]); kn = b2f(kp[2048]); vn = b2f(vp[2048]); }
    float p = rv * uv * kv;
    p += __shfl_xor(p, 1, 64);
    p += __shfl_xor(p, 2, 64);
    p += __shfl_xor(p, 4, 64);
    p += __shfl_xor(p, 8, 64);
    float yacc = p * vv;
#pragma unroll
    for (int ii = 0; ii < 16; ++ii) {
      float br = rdlane(rv, ii);
      float bk = rdlane(kv, ii);
      yacc = fmaf(br, S[ii], yacc);
      S[ii] = fmaf(S[ii], sw[ii], bk * vv);
    }
    red[t & 1][w * 64 + lane] = yacc;
    __syncthreads();
    if (w == 0) {
      const float* rb_ = red[t & 1];
      yp[0] = f2b(rb_[lane] + rb_[64 + lane] + rb_[128 + lane] + rb_[192 + lane]);
    }
    yp += 2048; rp += 2048; kp += 2048; vp += 2048;
    rv = rn; kv = kn; vv = vn;
  }
#pragma unroll
  for (int ii = 0; ii < 16; ++ii) wkv_out[stb + (size_t)ii * 64] = S[ii];
}

// =====================================================================
// GroupNorm per (b,t,h) over HS=64 (with /8 prescale), then * g.
// =====================================================================
__global__ __launch_bounds__(256) void gn_mul(const u16* __restrict__ y,
                                              const float* __restrict__ lnxw,
                                              const float* __restrict__ lnxb,
                                              const u16* __restrict__ g,
                                              u16* __restrict__ og)
{
  const int tid = threadIdx.x;
  const int wv = tid >> 6, j = tid & 63;
  const size_t gidx = (size_t)blockIdx.x * 4 + wv;
  const size_t bt = gidx >> 5;
  const int h = (int)(gidx & 31);
  const int c = h * 64 + j;
  float o = b2f(y[bt * 2048 + c]) * 0.125f;
  float s = o;
#pragma unroll
  for (int off = 32; off; off >>= 1) s += __shfl_xor(s, off, 64);
  const float m = s * (1.f / 64.f);
  const float d = o - m;
  float s2 = d * d;
#pragma unroll
  for (int off = 32; off; off >>= 1) s2 += __shfl_xor(s2, off, 64);
  const float var = s2 * (1.f / 64.f);
  float on = d * rsqrtf(var + 1e-5f);
  on = on * lnxw[c] + lnxb[c];
  og[bt * 2048 + c] = f2b(on * b2f(g[bt * 2048 + c]));
}

// =====================================================================
extern "C" void kernel_launch(void* const* d_in, const int* in_sizes, int n_in,
                              void* d_out, int out_size, void* d_ws, size_t ws_size,
                              hipStream_t stream)
{
  const float* x    = (const float*)d_in[0];
  const float* att0 = (const float*)d_in[1];
  const float* ffn0 = (const float*)d_in[2];
  const float* wkv0 = (const float*)d_in[3];
  const float* ln0w = (const float*)d_in[4];
  const float* ln0b = (const float*)d_in[5];
  const float* ln1w = (const float*)d_in[6];
  const float* ln1b = (const float*)d_in[7];
  const float* ln2w = (const float*)d_in[8];
  const float* ln2b = (const float*)d_in[9];
  const float* tmk  = (const float*)d_in[10];
  const float* tmv  = (const float*)d_in[11];
  const float* tmr  = (const float*)d_in[12];
  const float* tmg  = (const float*)d_in[13];
  const float* td   = (const float*)d_in[14];
  const float* tf   = (const float*)d_in[15];
  const float* Wg   = (const float*)d_in[16];
  const float* Wr   = (const float*)d_in[17];
  const float* Wk   = (const float*)d_in[18];
  const float* Wv   = (const float*)d_in[19];
  const float* Wo   = (const float*)d_in[20];
  const float* lnxw = (const float*)d_in[21];
  const float* lnxb = (const float*)d_in[22];
  const float* ftmk = (const float*)d_in[23];
  const float* ftmr = (const float*)d_in[24];
  const float* fWk  = (const float*)d_in[25];
  const float* fWr  = (const float*)d_in[26];
  const float* fWv  = (const float*)d_in[27];

  // ws layout (u16 elems; 1 MiB = 524288). Peak 320 MiB (known safe).
  u16* ws = (u16*)d_ws;
  auto seg = [&](size_t mib) { return ws + mib * 524288ull; };
  u16* A_ = seg(0);     // x0 -> x1 (bf16)
  u16* B_ = seg(64);
  u16* C_ = seg(128);
  u16* D_ = seg(192);
  u16* WT = seg(256);   // 64 MiB weight region (re-packed per phase)
  // attention: Wr,Wk,Wv,Wg,Wo bf16 (8 MiB each)
  u16* w_r = WT;
  u16* w_k = WT + 4194304ull;
  u16* w_v = WT + 8388608ull;
  u16* w_g = WT + 12582912ull;
  u16* w_o = WT + 16777216ull;
  // ffn: fWr (8 MiB), fWk (28), fWv (28)
  u16* w_fr = WT;
  u16* w_fk = WT + 4194304ull;
  u16* w_fv = WT + 18874368ull;
  u16* KK = C_;         // 28 MiB kk chunk (C_ dead by then)

  float* out_x   = (float*)d_out;
  float* out_ffn = out_x + 33554432ull;
  float* out_att = out_ffn + 16384ull;
  float* out_wkv = out_att + 16384ull;
  // d_out x-region (128 MiB f32) as two 64-MiB bf16 scratch slots:
  u16* OUT0 = (u16*)d_out;              // xg, then y
  u16* OUT1 = OUT0 + 33554432ull;       // rb

  const dim3 b256(256);
  const dim3 g2048(16, 128);
  const dim3 gKK(56, 16);   // N=7168, M=2048 chunk
  const dim3 gKV(16, 16);   // N=2048, M=2048 chunk

  // ---- attention ----
  cvt_f32_bf16<<<4096, b256, 0, stream>>>(Wr, w_r, 1048576);
  cvt_f32_bf16<<<4096, b256, 0, stream>>>(Wk, w_k, 1048576);
  cvt_f32_bf16<<<4096, b256, 0, stream>>>(Wv, w_v, 1048576);
  cvt_f32_bf16<<<4096, b256, 0, stream>>>(Wg, w_g, 1048576);
  cvt_f32_bf16<<<4096, b256, 0, stream>>>(Wo, w_o, 1048576);
  ln_plain<<<16384, b256, 0, stream>>>(x, ln0w, ln0b, A_);
  ln_mix<4><<<16384, b256, 0, stream>>>(A_, ln1w, ln1b, att0, tmk, tmv, tmr, tmg,
                                        B_, C_, D_, OUT0, out_att); // xk,xv,xr,xg
  gemm_bt<0,false><<<g2048, b256, 0, stream>>>(D_,   w_r, OUT1, nullptr, nullptr, 16384, 2048, 2048); // rb
  gemm_bt<0,false><<<g2048, b256, 0, stream>>>(B_,   w_k, D_,   nullptr, nullptr, 16384, 2048, 2048); // kb
  gemm_bt<0,false><<<g2048, b256, 0, stream>>>(C_,   w_v, B_,   nullptr, nullptr, 16384, 2048, 2048); // vb
  gemm_bt<1,false><<<g2048, b256, 0, stream>>>(OUT0, w_g, C_,   nullptr, nullptr, 16384, 2048, 2048); // gb (silu)
  wkv_scan<<<256, b256, 0, stream>>>(OUT1, D_, B_, td, tf, wkv0, OUT0, out_wkv);  // y -> OUT0
  gn_mul<<<131072, b256, 0, stream>>>(OUT0, lnxw, lnxb, C_, B_);                  // og -> B_
  gemm_bt<4,false><<<g2048, b256, 0, stream>>>(B_, w_o, A_, A_, nullptr, 16384, 2048, 2048); // x1 = x0+att

  // ---- ffn ----
  ln_mix<2><<<16384, b256, 0, stream>>>(A_, ln2w, ln2b, ffn0, ftmk, ftmr, nullptr, nullptr,
                                        B_, C_, nullptr, nullptr, out_ffn);  // xk2=B_, xr2=C_
  cvt_f32_bf16<<<4096, b256, 0, stream>>>(fWr, w_fr, 1048576);
  gemm_bt<3,false><<<g2048, b256, 0, stream>>>(C_, w_fr, D_, nullptr, nullptr, 16384, 2048, 2048); // rr (sigmoid)
  cvt_f32_bf16<<<14336, b256, 0, stream>>>(fWk, w_fk, 3670016);
  cvt_f32_bf16<<<14336, b256, 0, stream>>>(fWv, w_fv, 3670016);
  for (int h = 0; h < 8; ++h) {
    const size_t off = (size_t)h * 2048 * 2048;
    gemm_bt<2,false><<<gKK, b256, 0, stream>>>(B_ + off, w_fk, KK, nullptr, nullptr,
                                               2048, 7168, 2048);                 // kk chunk (relu^2)
    gemm_bt<5,true><<<gKV, b256, 0, stream>>>(KK, w_fv, out_x + off, A_ + off, D_ + off,
                                              2048, 2048, 7168);                  // x + sig*kv (f32 out)
  }
}